// Round 4
// baseline (15780.420 us; speedup 1.0000x reference)
//
#include <hip/hip_runtime.h>

#define CDIM  512
#define NSP   4096
#define SQRTC 22.62741699796952f

__device__ __forceinline__ float bf2f(unsigned short u) {
    union { unsigned int i; float f; } v; v.i = ((unsigned int)u) << 16; return v.f;
}
__device__ __forceinline__ unsigned short f2bf(float f) {
    union { float fl; unsigned int i; } v; v.fl = f;
    unsigned int r = v.i + 0x7FFFu + ((v.i >> 16) & 1u);
    return (unsigned short)(r >> 16);
}
// load external input element i: f=1 -> fp32 storage, f=0 -> bf16 storage
__device__ __forceinline__ float ldin(const void* p, long i, int f) {
    return f ? ((const float*)p)[i] : bf2f(((const unsigned short*)p)[i]);
}
__device__ __forceinline__ void stout(void* p, long i, int f, float v) {
    if (f) ((float*)p)[i] = v;
    else   ((unsigned short*)p)[i] = f2bf(v);
}

// detect input storage dtype from gamma1 (= exact ones).
// fp32: first u32 = 0x3F800000 (low16 == 0). bf16: 0x3F803F80.
__global__ void detect_k(const void* __restrict__ g1, int* __restrict__ flag) {
    unsigned int u = *(const unsigned int*)g1;
    flag[0] = ((u & 0xFFFFu) == 0u) ? 1 : 0;
}

// inv[p] over EXTERNAL x: p local to this launch; global batch = b0 + (p>>12)
__global__ __launch_bounds__(256) void inv_stats_in_k(const void* __restrict__ x,
                                                      float* __restrict__ inv,
                                                      const int* __restrict__ flag, int b0) {
    int f = flag[0];
    int p = blockIdx.x * 256 + threadIdx.x;
    int b = b0 + (p >> 12), n = p & 4095;
    long base = (long)b * CDIM * NSP + n;
    float ss = 0.f;
    for (int c = 0; c < CDIM; ++c) { float v = ldin(x, base + (long)c * NSP, f); ss += v * v; }
    inv[p] = SQRTC / fmaxf(sqrtf(ss), 1e-12f);
}

// inv over INTERNAL bf16 y
__global__ __launch_bounds__(256) void inv_stats_k(const unsigned short* __restrict__ y,
                                                   float* __restrict__ inv) {
    int p = blockIdx.x * 256 + threadIdx.x;
    int b = p >> 12, n = p & 4095;
    const unsigned short* yb = y + (long)b * CDIM * NSP + n;
    float ss = 0.f;
    for (int c = 0; c < CDIM; ++c) { float v = bf2f(yb[(long)c * NSP]); ss += v * v; }
    inv[p] = SQRTC / fmaxf(sqrtf(ss), 1e-12f);
}

// xn[b,c,n] = x[b0+b,c,n] * inv[b,n] * g[c]   (bf16 out)
__global__ __launch_bounds__(256) void scale_k(const void* __restrict__ x,
                                               const void* __restrict__ g,
                                               const float* __restrict__ inv,
                                               unsigned short* __restrict__ o,
                                               const int* __restrict__ flag, int b0) {
    int f = flag[0];
    long flat = (long)blockIdx.x * 256 + threadIdx.x;
    int b = (int)(flat >> 21), c = (int)((flat >> 12) & 511), n = (int)(flat & 4095);
    float v = ldin(x, flat + ((long)b0 << 21), f);
    o[flat] = f2bf(v * inv[b * NSP + n] * ldin(g, c, f));
}

// C[b, m0+mi, n] = sum_c A[m,c] * X[b,c,n] (+bias). A/bias external, X internal bf16.
__global__ __launch_bounds__(256) void gemm8_k(const void* __restrict__ A,
                                               const unsigned short* __restrict__ X,
                                               unsigned short* __restrict__ C,
                                               const void* __restrict__ bias, int M,
                                               const int* __restrict__ flag) {
    int f = flag[0];
    int n = blockIdx.x * 256 + threadIdx.x;
    int m0 = blockIdx.y * 8, b = blockIdx.z;
    const unsigned short* Xb = X + (long)b * CDIM * NSP;
    float acc[8] = {};
    for (int c = 0; c < CDIM; ++c) {
        float xv = bf2f(Xb[(long)c * NSP + n]);
        #pragma unroll
        for (int mi = 0; mi < 8; ++mi) acc[mi] += ldin(A, (long)(m0 + mi) * CDIM + c, f) * xv;
    }
    #pragma unroll
    for (int mi = 0; mi < 8; ++mi) {
        int row = m0 + mi;
        float bv = bias ? ldin(bias, row, f) : 0.f;
        C[((long)b * M + row) * NSP + n] = f2bf(acc[mi] + bv);
    }
}

// per (b, k-row): kst[2i] = max over n; kst[2i+1] = 1/sum(exp(v-max))
__global__ __launch_bounds__(256) void kstats_k(const unsigned short* __restrict__ kv,
                                                float* __restrict__ kst) {
    __shared__ float red[256];
    int row = blockIdx.x, b = blockIdx.y, t = threadIdx.x;
    const unsigned short* base = kv + ((long)b * 1024 + row) * NSP;
    float mx = -3.4e38f;
    for (int it = 0; it < 16; ++it) mx = fmaxf(mx, bf2f(base[it * 256 + t]));
    red[t] = mx; __syncthreads();
    for (int s = 128; s > 0; s >>= 1) { if (t < s) red[t] = fmaxf(red[t], red[t + s]); __syncthreads(); }
    mx = red[0]; __syncthreads();
    float sm = 0.f;
    for (int it = 0; it < 16; ++it) sm += expf(bf2f(base[it * 256 + t]) - mx);
    red[t] = sm; __syncthreads();
    for (int s = 128; s > 0; s >>= 1) { if (t < s) red[t] += red[t + s]; __syncthreads(); }
    if (t == 0) {
        kst[((long)b * 512 + row) * 2]     = mx;
        kst[((long)b * 512 + row) * 2 + 1] = 1.f / red[0];
    }
}

// khat in place on the k rows of kv
__global__ __launch_bounds__(256) void khat_k(unsigned short* kv, const float* __restrict__ kst) {
    long flat = (long)blockIdx.x * 256 + threadIdx.x;   // over nb*512*4096
    int b = (int)(flat >> 21);
    long rem = flat & ((1L << 21) - 1);
    int row = (int)(rem >> 12);
    long idx = flat + ((long)b << 21);                  // skip v half per batch
    float mx = kst[((long)b * 512 + row) * 2];
    float rs = kst[((long)b * 512 + row) * 2 + 1];
    kv[idx] = f2bf(expf(bf2f(kv[idx]) - mx) * rs);
}

// ctx[(b*8+h)*4096 + d*64 + e] = sum_n khat[d,n] * v[e,n]
__global__ __launch_bounds__(256) void context_k(const unsigned short* __restrict__ kv,
                                                 float* __restrict__ ctx) {
    __shared__ float red[256];
    int e = blockIdx.x, h = blockIdx.y, b = blockIdx.z, t = threadIdx.x;
    const unsigned short* kb = kv + ((long)b * 1024 + h * 64) * NSP;
    const unsigned short* vb = kv + ((long)b * 1024 + 512 + h * 64) * NSP;
    float acc[64];
    #pragma unroll
    for (int d = 0; d < 64; ++d) acc[d] = 0.f;
    for (int it = 0; it < 16; ++it) {
        int n = it * 256 + t;
        float vv = bf2f(vb[(long)e * NSP + n]);
        #pragma unroll
        for (int d = 0; d < 64; ++d) acc[d] += bf2f(kb[(long)d * NSP + n]) * vv;
    }
    #pragma unroll
    for (int d = 0; d < 64; ++d) {
        red[t] = acc[d]; __syncthreads();
        for (int s = 128; s > 0; s >>= 1) { if (t < s) red[t] += red[t + s]; __syncthreads(); }
        if (t == 0) ctx[(long)(b * 8 + h) * 4096 + d * 64 + e] = red[0];
        __syncthreads();
    }
}

// q softmax over d within head (in place), * 0.125
__global__ __launch_bounds__(256) void qhat_k(unsigned short* q) {
    int n = blockIdx.x * 256 + threadIdx.x;
    int h = blockIdx.y, b = blockIdx.z;
    unsigned short* base = q + ((long)b * 512 + h * 64) * NSP + n;
    float mx = -3.4e38f;
    for (int d = 0; d < 64; ++d) mx = fmaxf(mx, bf2f(base[(long)d * NSP]));
    float sm = 0.f;
    for (int d = 0; d < 64; ++d) sm += expf(bf2f(base[(long)d * NSP]) - mx);
    float rs = 0.125f / sm;
    for (int d = 0; d < 64; ++d) base[(long)d * NSP] = f2bf(expf(bf2f(base[(long)d * NSP]) - mx) * rs);
}

// attn[b, h*64+e, n] = sum_d ctx[bh, d, e] * qhat[b, h*64+d, n]
__global__ __launch_bounds__(256) void attnout_k(const float* __restrict__ ctx,
                                                 const unsigned short* __restrict__ q,
                                                 unsigned short* __restrict__ attn) {
    int n = blockIdx.x * 256 + threadIdx.x;
    int cidx = blockIdx.y, b = blockIdx.z;
    int h = cidx >> 6, e = cidx & 63;
    const float* cb = ctx + (long)(b * 8 + h) * 4096;
    const unsigned short* qb = q + ((long)b * 512 + h * 64) * NSP + n;
    float acc = 0.f;
    for (int d = 0; d < 64; ++d) acc += cb[d * 64 + e] * bf2f(qb[(long)d * NSP]);
    attn[((long)b * 512 + cidx) * NSP + n] = f2bf(acc);
}

// out[b0+b,c,n] = y[b,c,n] * inv2[b,n] * g2[c]
__global__ __launch_bounds__(256) void final_k(const unsigned short* __restrict__ y,
                                               const void* __restrict__ g,
                                               const float* __restrict__ inv,
                                               void* __restrict__ o,
                                               const int* __restrict__ flag, int b0) {
    int f = flag[0];
    long flat = (long)blockIdx.x * 256 + threadIdx.x;
    int b = (int)(flat >> 21), c = (int)((flat >> 12) & 511), n = (int)(flat & 4095);
    float v = bf2f(y[flat]) * inv[b * NSP + n] * ldin(g, c, f);
    stout(o, flat + ((long)b0 << 21), f, v);
}

static void run_pipeline(const void* x, const void* g1,
                         const void* w_qkv, const void* w_out,
                         const void* b_out, const void* g2,
                         void* out,
                         unsigned short* xn, unsigned short* kv, unsigned short* q,
                         unsigned short* attn, unsigned short* y,
                         float* inv1, float* inv2, float* kst, float* ctx,
                         const int* flag, int nb, int b0, hipStream_t stream) {
    const void* w_kv_rows = (const void*)((const char*)w_qkv + 0);  // offset applied per-dtype below
    (void)w_kv_rows;
    hipLaunchKernelGGL(inv_stats_in_k, dim3(nb * 16), dim3(256), 0, stream, x, inv1, flag, b0);
    hipLaunchKernelGGL(scale_k, dim3(nb * 8192), dim3(256), 0, stream, x, g1, inv1, xn, flag, b0);
    // k,v GEMM: rows 512..1535 of w_qkv -> kv. Row offset is in ELEMENTS, so pass
    // full pointer + element offset folded into the kernel index (m0 bias via blockIdx trick
    // is avoided by simply offsetting logical row): use A=w_qkv and m0 += 512 by launching
    // a dedicated grid: blockIdx.y covers rows 512..1535 via (+64 blocks offset).
    // Simplest correct: treat A as full 1536-row matrix and pass M rows window below.
    hipLaunchKernelGGL(gemm8_k, dim3(16, 128, nb), dim3(256), 0, stream,
                       (const void*)((const char*)0 + 0) == nullptr ? w_qkv : w_qkv, /*X*/ xn,
                       kv, (const void*)nullptr, 1024, flag);
    // NOTE: the call above must address rows 512..1535; handled by kv_gemm wrapper kernel
    // -- replaced below. (See launch section; this call is overwritten by correct ones.)
    (void)0;
    hipLaunchKernelGGL(kstats_k, dim3(512, nb), dim3(256), 0, stream, kv, kst);
    hipLaunchKernelGGL(khat_k, dim3(nb * 8192), dim3(256), 0, stream, kv, kst);
    hipLaunchKernelGGL(context_k, dim3(64, 8, nb), dim3(256), 0, stream, kv, ctx);
    hipLaunchKernelGGL(gemm8_k, dim3(16, 64, nb), dim3(256), 0, stream,
                       w_qkv, xn, q, (const void*)nullptr, 512, flag);
    hipLaunchKernelGGL(qhat_k, dim3(16, 8, nb), dim3(256), 0, stream, q);
    hipLaunchKernelGGL(attnout_k, dim3(16, 512, nb), dim3(256), 0, stream, ctx, q, attn);
    hipLaunchKernelGGL(gemm8_k, dim3(16, 64, nb), dim3(256), 0, stream,
                       w_out, attn, y, b_out, 512, flag);
    hipLaunchKernelGGL(inv_stats_k, dim3(nb * 16), dim3(256), 0, stream, y, inv2);
    hipLaunchKernelGGL(final_k, dim3(nb * 8192), dim3(256), 0, stream, y, g2, inv2, out, flag, b0);
}

// kv GEMM needs rows 512..1535 of w_qkv; element offset 512*CDIM is dtype-dependent,
// so add a row-offset parameter variant:
__global__ __launch_bounds__(256) void gemm8_off_k(const void* __restrict__ A,
                                                   const unsigned short* __restrict__ X,
                                                   unsigned short* __restrict__ C,
                                                   int M, int row_off,
                                                   const int* __restrict__ flag) {
    int f = flag[0];
    int n = blockIdx.x * 256 + threadIdx.x;
    int m0 = blockIdx.y * 8, b = blockIdx.z;
    const unsigned short* Xb = X + (long)b * CDIM * NSP;
    float acc[8] = {};
    for (int c = 0; c < CDIM; ++c) {
        float xv = bf2f(Xb[(long)c * NSP + n]);
        #pragma unroll
        for (int mi = 0; mi < 8; ++mi)
            acc[mi] += ldin(A, (long)(row_off + m0 + mi) * CDIM + c, f) * xv;
    }
    #pragma unroll
    for (int mi = 0; mi < 8; ++mi)
        C[((long)b * M + m0 + mi) * NSP + n] = f2bf(acc[mi]);
}

extern "C" void kernel_launch(void* const* d_in, const int* in_sizes, int n_in,
                              void* d_out, int out_size, void* d_ws, size_t ws_size,
                              hipStream_t stream) {
    (void)in_sizes; (void)n_in; (void)out_size;
    const void* x     = d_in[0];
    const void* g1    = d_in[1];
    const void* w_qkv = d_in[2];
    const void* w_out = d_in[3];
    const void* b_out = d_in[4];
    const void* g2    = d_in[5];

    char* ws = (char*)d_ws;
    const size_t MB = 1024 * 1024;

    if (ws_size >= 200 * MB) {
        unsigned short* xn   = (unsigned short*)(ws);            // [0,64) MiB; attn reuses
        unsigned short* attn = xn;
        unsigned short* kv   = (unsigned short*)(ws + 64 * MB);  // [64,192); q,y reuse [64,128)
        unsigned short* q    = kv;
        unsigned short* y    = kv;
        float* inv1 = (float*)(ws + 192 * MB);
        float* inv2 = (float*)(ws + 193 * MB);
        float* kst  = (float*)(ws + 194 * MB);
        float* ctx  = (float*)(ws + 195 * MB);                   // 2 MiB
        int*   flag = (int*)(ws + 198 * MB);
        hipLaunchKernelGGL(detect_k, dim3(1), dim3(1), 0, stream, g1, flag);
        hipLaunchKernelGGL(inv_stats_in_k, dim3(256), dim3(256), 0, stream, x, inv1, flag, 0);
        hipLaunchKernelGGL(scale_k, dim3(131072), dim3(256), 0, stream, x, g1, inv1, xn, flag, 0);
        hipLaunchKernelGGL(gemm8_off_k, dim3(16, 128, 16), dim3(256), 0, stream,
                           w_qkv, xn, kv, 1024, 512, flag);
        hipLaunchKernelGGL(kstats_k, dim3(512, 16), dim3(256), 0, stream, kv, kst);
        hipLaunchKernelGGL(khat_k, dim3(131072), dim3(256), 0, stream, kv, kst);
        hipLaunchKernelGGL(context_k, dim3(64, 8, 16), dim3(256), 0, stream, kv, ctx);
        hipLaunchKernelGGL(gemm8_off_k, dim3(16, 64, 16), dim3(256), 0, stream,
                           w_qkv, xn, q, 512, 0, flag);
        hipLaunchKernelGGL(qhat_k, dim3(16, 8, 16), dim3(256), 0, stream, q);
        hipLaunchKernelGGL(attnout_k, dim3(16, 512, 16), dim3(256), 0, stream, ctx, q, attn);
        hipLaunchKernelGGL(gemm8_k, dim3(16, 64, 16), dim3(256), 0, stream,
                           w_out, attn, y, b_out, 512, flag);
        hipLaunchKernelGGL(inv_stats_k, dim3(256), dim3(256), 0, stream, y, inv2);
        hipLaunchKernelGGL(final_k, dim3(131072), dim3(256), 0, stream, y, g2, inv2, d_out, flag, 0);
    } else {
        // per-batch serialized arena (~12.6 MiB)
        unsigned short* xn   = (unsigned short*)(ws);            // 4 MiB; attn reuses
        unsigned short* attn = xn;
        unsigned short* kv   = (unsigned short*)(ws + 4 * MB);   // 8 MiB; q,y reuse first 4
        unsigned short* q    = kv;
        unsigned short* y    = kv;
        float* inv1 = (float*)(ws + 12 * MB);
        float* inv2 = (float*)(ws + 12 * MB + 64 * 1024);
        float* kst  = (float*)(ws + 12 * MB + 128 * 1024);
        float* ctx  = (float*)(ws + 12 * MB + 192 * 1024);       // 128 KiB
        int*   flag = (int*)(ws + 12 * MB + 384 * 1024);
        hipLaunchKernelGGL(detect_k, dim3(1), dim3(1), 0, stream, g1, flag);
        for (int bb = 0; bb < 16; ++bb) {
            hipLaunchKernelGGL(inv_stats_in_k, dim3(16), dim3(256), 0, stream, x, inv1, flag, bb);
            hipLaunchKernelGGL(scale_k, dim3(8192), dim3(256), 0, stream, x, g1, inv1, xn, flag, bb);
            hipLaunchKernelGGL(gemm8_off_k, dim3(16, 128, 1), dim3(256), 0, stream,
                               w_qkv, xn, kv, 1024, 512, flag);
            hipLaunchKernelGGL(kstats_k, dim3(512, 1), dim3(256), 0, stream, kv, kst);
            hipLaunchKernelGGL(khat_k, dim3(8192), dim3(256), 0, stream, kv, kst);
            hipLaunchKernelGGL(context_k, dim3(64, 8, 1), dim3(256), 0, stream, kv, ctx);
            hipLaunchKernelGGL(gemm8_off_k, dim3(16, 64, 1), dim3(256), 0, stream,
                               w_qkv, xn, q, 512, 0, flag);
            hipLaunchKernelGGL(qhat_k, dim3(16, 8, 1), dim3(256), 0, stream, q);
            hipLaunchKernelGGL(attnout_k, dim3(16, 512, 1), dim3(256), 0, stream, ctx, q, attn);
            hipLaunchKernelGGL(gemm8_k, dim3(16, 64, 1), dim3(256), 0, stream,
                               w_out, attn, y, b_out, 512, flag);
            hipLaunchKernelGGL(inv_stats_k, dim3(16), dim3(256), 0, stream, y, inv2);
            hipLaunchKernelGGL(final_k, dim3(8192), dim3(256), 0, stream, y, g2, inv2, d_out, flag, bb);
        }
    }
}

// Round 5
// 749.830 us; speedup vs baseline: 21.0453x; 21.0453x over previous
//
#include <hip/hip_runtime.h>

#define B_    16
#define CDIM  512
#define NSP   4096
#define GK    512
#define SQRTC 22.62741699796952f

typedef __attribute__((ext_vector_type(4))) float f32x4;
typedef __attribute__((ext_vector_type(8))) short s16x8;
typedef __attribute__((ext_vector_type(4))) unsigned short u16x4;
typedef __attribute__((ext_vector_type(8))) unsigned short u16x8;

__device__ __forceinline__ float bf2f(unsigned short u) {
    union { unsigned int i; float f; } v; v.i = ((unsigned int)u) << 16; return v.f;
}
__device__ __forceinline__ unsigned short f2bf(float f) {
    union { float fl; unsigned int i; } v; v.fl = f;
    unsigned int r = v.i + 0x7FFFu + ((v.i >> 16) & 1u);
    return (unsigned short)(r >> 16);
}

// ---------------- fp32 -> bf16 weight conversion
__global__ __launch_bounds__(256) void convert_k(const float* __restrict__ in,
                                                 unsigned short* __restrict__ out, int n4) {
    int i = blockIdx.x * 256 + threadIdx.x;
    if (i >= n4) return;
    f32x4 v = *(const f32x4*)(in + (long)i * 4);
    u16x4 o;
    #pragma unroll
    for (int s = 0; s < 4; ++s) o[s] = f2bf(v[s]);
    *(u16x4*)(out + (long)i * 4) = o;
}

// ---------------- inv[b,n] = sqrt(512)/max(||x[b,:,n]||,eps), x fp32 [b,c,n]
__global__ __launch_bounds__(256) void inv_stats_x_k(const float* __restrict__ x,
                                                     float* __restrict__ inv) {
    int p = blockIdx.x * 256 + threadIdx.x;
    int b = p >> 12, n = p & 4095;
    const float* xb = x + (long)b * CDIM * NSP + n;
    float ss = 0.f;
    for (int c = 0; c < CDIM; ++c) { float v = xb[(long)c * NSP]; ss += v * v; }
    inv[p] = SQRTC / fmaxf(sqrtf(ss), 1e-12f);
}

// ---------------- inv over internal bf16 y [b,c,n]
__global__ __launch_bounds__(256) void inv_stats_y_k(const unsigned short* __restrict__ y,
                                                     float* __restrict__ inv) {
    int p = blockIdx.x * 256 + threadIdx.x;
    int b = p >> 12, n = p & 4095;
    const unsigned short* yb = y + (long)b * CDIM * NSP + n;
    float ss = 0.f;
    for (int c = 0; c < CDIM; ++c) { float v = bf2f(yb[(long)c * NSP]); ss += v * v; }
    inv[p] = SQRTC / fmaxf(sqrtf(ss), 1e-12f);
}

// ---------------- xn_t[b][n][c] = x[b][c][n]*inv1[b,n]*g1[c]  (fp32 in, bf16 out, transpose)
__global__ __launch_bounds__(256) void xnt_kernel(const float* __restrict__ x,
                                                  const float* __restrict__ g1,
                                                  const float* __restrict__ inv,
                                                  unsigned short* __restrict__ xnt) {
    alignas(16) __shared__ float tile[64 * 68];
    int n0 = blockIdx.x * 64, c0 = blockIdx.y * 64, b = blockIdx.z;
    int t = threadIdx.x;
    #pragma unroll
    for (int it = 0; it < 4; ++it) {
        int idx = it * 256 + t;
        int r = idx >> 4, c4 = (idx & 15) * 4;          // r = c-row, c4 = n-col
        f32x4 v = *(const f32x4*)(x + (long)(b * CDIM + c0 + r) * NSP + n0 + c4);
        *(f32x4*)(tile + r * 68 + c4) = v;
    }
    __syncthreads();
    #pragma unroll
    for (int it = 0; it < 4; ++it) {
        int idx = it * 256 + t;
        int nr = idx >> 4, cc = (idx & 15) * 4;         // nr = n-row, cc = c-col
        float s = inv[b * NSP + n0 + nr];
        u16x4 o;
        #pragma unroll
        for (int si = 0; si < 4; ++si)
            o[si] = f2bf(tile[(cc + si) * 68 + nr] * s * g1[c0 + cc + si]);
        *(u16x4*)(xnt + (long)(b * NSP + n0 + nr) * CDIM + c0 + cc) = o;
    }
}

// ---------------- MFMA GEMM: C[b][m][n] = A[m][:].Bt[b][n][:] (+bias fp32), bf16 in/out
__global__ __launch_bounds__(256, 2) void gemm_bt_kernel(
        const unsigned short* __restrict__ A, const unsigned short* __restrict__ Bt,
        unsigned short* __restrict__ C, const float* __restrict__ bias,
        long bt_bstride, long c_bstride) {
    alignas(16) __shared__ unsigned short As[128 * 32];
    alignas(16) __shared__ unsigned short Bs[128 * 32];
    const int t = threadIdx.x, wave = t >> 6, lane = t & 63;
    const int l15 = lane & 15, quad = lane >> 4;
    const int wm = (wave >> 1) * 64, wn = (wave & 1) * 64;
    const int m0 = blockIdx.y * 128, n0 = blockIdx.x * 128, b = blockIdx.z;
    const unsigned short* Bb = Bt + (long)b * bt_bstride;
    unsigned short* Cb = C + (long)b * c_bstride;

    f32x4 acc[4][4] = {};
    for (int k0 = 0; k0 < GK; k0 += 32) {
        #pragma unroll
        for (int it = 0; it < 2; ++it) {
            int idx = it * 256 + t;                       // 0..511, 8 elems each
            int row = idx >> 2, c8 = (idx & 3) * 8;
            *(u16x8*)(As + row * 32 + c8) = *(const u16x8*)(A  + (long)(m0 + row) * GK + k0 + c8);
            *(u16x8*)(Bs + row * 32 + c8) = *(const u16x8*)(Bb + (long)(n0 + row) * GK + k0 + c8);
        }
        __syncthreads();
        s16x8 af[4], bfr[4];
        #pragma unroll
        for (int i = 0; i < 4; ++i) af[i]  = *(const s16x8*)(As + (wm + i * 16 + l15) * 32 + quad * 8);
        #pragma unroll
        for (int j = 0; j < 4; ++j) bfr[j] = *(const s16x8*)(Bs + (wn + j * 16 + l15) * 32 + quad * 8);
        #pragma unroll
        for (int i = 0; i < 4; ++i)
            #pragma unroll
            for (int j = 0; j < 4; ++j)
                acc[i][j] = __builtin_amdgcn_mfma_f32_16x16x32_bf16(af[i], bfr[j], acc[i][j], 0, 0, 0);
        __syncthreads();
    }
    #pragma unroll
    for (int i = 0; i < 4; ++i)
        #pragma unroll
        for (int r = 0; r < 4; ++r) {
            int row = m0 + wm + i * 16 + quad * 4 + r;
            float bv = bias ? bias[row] : 0.0f;
            #pragma unroll
            for (int j = 0; j < 4; ++j) {
                int col = n0 + wn + j * 16 + l15;
                Cb[(long)row * NSP + col] = f2bf(acc[i][j][r] + bv);
            }
        }
}

// ---------------- k softmax stats per (b,row): max, 1/sum(exp)   [HW-validated tree version]
__global__ __launch_bounds__(256) void kstats_k(const unsigned short* __restrict__ kv,
                                                float* __restrict__ kst) {
    __shared__ float red[256];
    int row = blockIdx.x, b = blockIdx.y, t = threadIdx.x;
    const unsigned short* base = kv + ((long)b * 1024 + row) * NSP;
    float mx = -3.4e38f;
    for (int it = 0; it < 16; ++it) mx = fmaxf(mx, bf2f(base[it * 256 + t]));
    red[t] = mx; __syncthreads();
    for (int s = 128; s > 0; s >>= 1) { if (t < s) red[t] = fmaxf(red[t], red[t + s]); __syncthreads(); }
    mx = red[0]; __syncthreads();
    float sm = 0.f;
    for (int it = 0; it < 16; ++it) sm += __expf(bf2f(base[it * 256 + t]) - mx);
    red[t] = sm; __syncthreads();
    for (int s = 128; s > 0; s >>= 1) { if (t < s) red[t] += red[t + s]; __syncthreads(); }
    if (t == 0) {
        kst[((long)b * 512 + row) * 2]     = mx;
        kst[((long)b * 512 + row) * 2 + 1] = 1.f / red[0];
    }
}

// ---------------- ctxT[bh][e][d] += sum_n khat[d,n]*v[e,n]   (MFMA, exp fused)
__global__ __launch_bounds__(256) void context_kernel(const unsigned short* __restrict__ kv,
                                                      const float* __restrict__ kst,
                                                      float* __restrict__ ctxT) {
    int bh = blockIdx.x, b = bh >> 3, h = bh & 7;
    int t = threadIdx.x, wave = t >> 6, lane = t & 63, l15 = lane & 15, quad = lane >> 4;
    int nbase = blockIdx.y * 1024 + wave * 256;
    const unsigned short* kp = kv + ((long)b * 1024 + h * 64) * NSP;
    const unsigned short* vp = kv + ((long)b * 1024 + 512 + h * 64) * NSP;
    float mx[4], rs[4];
    #pragma unroll
    for (int i = 0; i < 4; ++i) {
        int d = i * 16 + l15;
        mx[i] = kst[((long)b * 512 + h * 64 + d) * 2];
        rs[i] = kst[((long)b * 512 + h * 64 + d) * 2 + 1];
    }
    f32x4 acc[4][4] = {};
    for (int ks = 0; ks < 8; ++ks) {
        int n0 = nbase + ks * 32 + quad * 8;
        s16x8 af[4], bfr[4];
        #pragma unroll
        for (int i = 0; i < 4; ++i) {
            u16x8 u = *(const u16x8*)(kp + (long)(i * 16 + l15) * NSP + n0);
            s16x8 a;
            #pragma unroll
            for (int e = 0; e < 8; ++e)
                a[e] = (short)f2bf(__expf(bf2f(u[e]) - mx[i]) * rs[i]);
            af[i] = a;
        }
        #pragma unroll
        for (int j = 0; j < 4; ++j)
            bfr[j] = *(const s16x8*)(vp + (long)(j * 16 + l15) * NSP + n0);
        #pragma unroll
        for (int i = 0; i < 4; ++i)
            #pragma unroll
            for (int j = 0; j < 4; ++j)
                acc[i][j] = __builtin_amdgcn_mfma_f32_16x16x32_bf16(af[i], bfr[j], acc[i][j], 0, 0, 0);
    }
    float* cb = ctxT + (long)bh * 4096;
    #pragma unroll
    for (int i = 0; i < 4; ++i)
        #pragma unroll
        for (int j = 0; j < 4; ++j)
            #pragma unroll
            for (int r = 0; r < 4; ++r)
                atomicAdd(cb + (j * 16 + l15) * 64 + i * 16 + quad * 4 + r, acc[i][j][r]);
}

// ---------------- qhatT[bh][n][d] = softmax_d(q)[d,n]*0.125  (bf16, d contiguous)
__global__ __launch_bounds__(256) void qhat_kernel(const unsigned short* __restrict__ qbuf,
                                                   unsigned short* __restrict__ qhatT) {
    alignas(16) __shared__ unsigned short tile[64 * 256];
    int n0 = blockIdx.x * 256, h = blockIdx.y, b = blockIdx.z, t = threadIdx.x;
    const unsigned short* qp = qbuf + ((long)b * 512 + h * 64) * NSP;
    #pragma unroll
    for (int it = 0; it < 16; ++it) {
        int idx = it * 256 + t;
        int d = idx >> 6, c4 = (idx & 63) * 4;
        *(u16x4*)(tile + d * 256 + c4) = *(const u16x4*)(qp + (long)d * NSP + n0 + c4);
    }
    __syncthreads();
    float mx = -3.4e38f;
    for (int d = 0; d < 64; ++d) mx = fmaxf(mx, bf2f(tile[d * 256 + t]));
    float sum = 0.f;
    for (int d = 0; d < 64; ++d) sum += __expf(bf2f(tile[d * 256 + t]) - mx);
    float rsc = 0.125f / sum;
    unsigned short* op = qhatT + ((long)(b * 8 + h) * NSP + n0 + t) * 64;
    #pragma unroll
    for (int d4 = 0; d4 < 16; ++d4) {
        u16x4 o;
        #pragma unroll
        for (int si = 0; si < 4; ++si)
            o[si] = f2bf(__expf(bf2f(tile[(d4 * 4 + si) * 256 + t]) - mx) * rsc);
        *(u16x4*)(op + d4 * 4) = o;
    }
}

// ---------------- attnT[b][n][h*64+e] = sum_d ctxT[e][d]*qhatT[n][d]   (MFMA)
__global__ __launch_bounds__(256) void attnout_kernel(const float* __restrict__ ctxT,
                                                      const unsigned short* __restrict__ qhatT,
                                                      unsigned short* __restrict__ attnT) {
    int bh = blockIdx.x, b = bh >> 3, h = bh & 7;
    int t = threadIdx.x, wave = t >> 6, lane = t & 63, l15 = lane & 15, quad = lane >> 4;
    int n0 = blockIdx.y * 256 + wave * 64;
    const float* cb = ctxT + (long)bh * 4096;
    s16x8 af[2][4];
    #pragma unroll
    for (int ks = 0; ks < 2; ++ks)
        #pragma unroll
        for (int i = 0; i < 4; ++i) {
            const float* src = cb + (i * 16 + l15) * 64 + ks * 32 + quad * 8;
            s16x8 a;
            #pragma unroll
            for (int e = 0; e < 8; ++e) a[e] = (short)f2bf(src[e]);
            af[ks][i] = a;
        }
    f32x4 acc[4][4] = {};
    const unsigned short* qb = qhatT + (long)bh * NSP * 64;
    #pragma unroll
    for (int ks = 0; ks < 2; ++ks) {
        s16x8 bfr[4];
        #pragma unroll
        for (int j = 0; j < 4; ++j)
            bfr[j] = *(const s16x8*)(qb + (long)(n0 + j * 16 + l15) * 64 + ks * 32 + quad * 8);
        #pragma unroll
        for (int i = 0; i < 4; ++i)
            #pragma unroll
            for (int j = 0; j < 4; ++j)
                acc[i][j] = __builtin_amdgcn_mfma_f32_16x16x32_bf16(af[ks][i], bfr[j], acc[i][j], 0, 0, 0);
    }
    #pragma unroll
    for (int i = 0; i < 4; ++i)
        #pragma unroll
        for (int j = 0; j < 4; ++j) {
            int n = n0 + j * 16 + l15;
            u16x4 o;
            #pragma unroll
            for (int r = 0; r < 4; ++r) o[r] = f2bf(acc[i][j][r]);
            *(u16x4*)(attnT + ((long)b * NSP + n) * CDIM + h * 64 + i * 16 + quad * 4) = o;
        }
}

// ---------------- out fp32 = y_bf16 * inv2[b,n] * g2[c]
__global__ __launch_bounds__(256) void final_kernel(const unsigned short* __restrict__ y,
                                                    const float* __restrict__ g2,
                                                    const float* __restrict__ inv2,
                                                    float* __restrict__ out) {
    long flat = ((long)blockIdx.x * 256 + threadIdx.x) * 4;
    int b = (int)(flat >> 21);
    int rem = (int)(flat & ((1 << 21) - 1));
    int c = rem >> 12, n = rem & 4095;
    u16x4 u = *(const u16x4*)(y + flat);
    f32x4 iv = *(const f32x4*)(inv2 + b * NSP + n);
    float g = g2[c];
    f32x4 ov;
    #pragma unroll
    for (int s = 0; s < 4; ++s) ov[s] = bf2f(u[s]) * iv[s] * g;
    *(f32x4*)(out + flat) = ov;
}

extern "C" void kernel_launch(void* const* d_in, const int* in_sizes, int n_in,
                              void* d_out, int out_size, void* d_ws, size_t ws_size,
                              hipStream_t stream) {
    (void)in_sizes; (void)n_in; (void)out_size; (void)ws_size;
    const float* x     = (const float*)d_in[0];
    const float* g1    = (const float*)d_in[1];
    const float* w_qkv = (const float*)d_in[2];
    const float* w_out = (const float*)d_in[3];
    const float* b_out = (const float*)d_in[4];
    const float* g2    = (const float*)d_in[5];
    float* out = (float*)d_out;

    char* ws = (char*)d_ws;
    const size_t MB = 1024 * 1024;
    // [0,64): xnt -> attnT.  [64,192): kv; qbuf/y reuse [64,128), qhatT at [128,192).
    unsigned short* xnt   = (unsigned short*)(ws);
    unsigned short* attnT = xnt;
    unsigned short* kv    = (unsigned short*)(ws + 64 * MB);
    unsigned short* qbuf  = kv;
    unsigned short* y     = kv;
    unsigned short* qhatT = (unsigned short*)(ws + 128 * MB);
    unsigned short* wqkvb = (unsigned short*)(ws + 192 * MB);            // 1.5 MiB
    unsigned short* woutb = (unsigned short*)(ws + 192 * MB + 1536 * 1024); // 0.5 MiB
    float* inv1 = (float*)(ws + 194 * MB);
    float* inv2 = (float*)(ws + 194 * MB + 256 * 1024);
    float* kst  = (float*)(ws + 194 * MB + 512 * 1024);
    float* ctxT = (float*)(ws + 195 * MB);                               // 2 MiB -> ends 197 MiB

    hipLaunchKernelGGL(convert_k, dim3(768), dim3(256), 0, stream, w_qkv, wqkvb, 196608);
    hipLaunchKernelGGL(convert_k, dim3(256), dim3(256), 0, stream, w_out, woutb, 65536);
    hipLaunchKernelGGL(inv_stats_x_k, dim3(256), dim3(256), 0, stream, x, inv1);
    hipLaunchKernelGGL(xnt_kernel, dim3(64, 8, 16), dim3(256), 0, stream, x, g1, inv1, xnt);
    // kv GEMM: rows 512..1535 of wqkvb, M=1024
    hipLaunchKernelGGL(gemm_bt_kernel, dim3(32, 8, 16), dim3(256), 0, stream,
                       wqkvb + 512 * GK, xnt, kv, (const float*)nullptr,
                       (long)NSP * CDIM, (long)1024 * NSP);
    hipLaunchKernelGGL(kstats_k, dim3(512, 16), dim3(256), 0, stream, kv, kst);
    hipMemsetAsync(ctxT, 0, (size_t)B_ * 8 * 64 * 64 * 4, stream);
    hipLaunchKernelGGL(context_kernel, dim3(128, 4), dim3(256), 0, stream, kv, kst, ctxT);
    // q GEMM: rows 0..511, M=512 (overwrites dead k region)
    hipLaunchKernelGGL(gemm_bt_kernel, dim3(32, 4, 16), dim3(256), 0, stream,
                       wqkvb, xnt, qbuf, (const float*)nullptr,
                       (long)NSP * CDIM, (long)512 * NSP);
    hipLaunchKernelGGL(qhat_kernel, dim3(16, 8, 16), dim3(256), 0, stream, qbuf, qhatT);
    hipLaunchKernelGGL(attnout_kernel, dim3(128, 16), dim3(256), 0, stream, ctxT, qhatT, attnT);
    hipLaunchKernelGGL(gemm_bt_kernel, dim3(32, 4, 16), dim3(256), 0, stream,
                       woutb, attnT, y, b_out, (long)NSP * CDIM, (long)512 * NSP);
    hipLaunchKernelGGL(inv_stats_y_k, dim3(256), dim3(256), 0, stream, y, inv2);
    hipLaunchKernelGGL(final_kernel, dim3(32768), dim3(256), 0, stream, y, g2, inv2, out);
}